// Round 15
// baseline (560.483 us; speedup 1.0000x reference)
//
#include <hip/hip_runtime.h>
#include <hip/hip_fp16.h>

#define EMB_C 64
#define N_USER_C 100000
#define BROWS 256        // rows per bucket
#define BSHIFT 8
#define COLBITS 18       // col fits 18 bits (n_nodes <= 262144)
#define NBMAX 640        // max buckets supported (padded hist row)

// ============================ CSR path kernels ============================

// x0h = fp16(concat(user_emb, item_emb)).
__global__ __launch_bounds__(256) void fill_h_kernel(
        const float4* __restrict__ ue, const float4* __restrict__ ie,
        ushort4* __restrict__ x0, long long u4, long long t4) {
    long long i = (long long)blockIdx.x * blockDim.x + threadIdx.x;
    if (i >= t4) return;
    float4 v = (i < u4) ? ue[i] : ie[i - u4];
    ushort4 h;
    h.x = __half_as_ushort(__float2half(v.x));
    h.y = __half_as_ushort(__float2half(v.y));
    h.z = __half_as_ushort(__float2half(v.z));
    h.w = __half_as_ushort(__float2half(v.w));
    x0[i] = h;
}

// Per-chunk bucket histogram -> ghist[chunk][b] (coalesced, no global atomics).
__global__ __launch_bounds__(256) void chunkhist_kernel(
        const int* __restrict__ rows, int* __restrict__ ghist, int nnz, int nb,
        int csz) {
    __shared__ int hist[NBMAX];
    for (int b = threadIdx.x; b < nb; b += 256) hist[b] = 0;
    __syncthreads();
    const long long c0 = (long long)blockIdx.x * csz;
    for (int i = threadIdx.x; i < csz; i += 256) {
        long long e = c0 + i;
        if (e < nnz) atomicAdd(&hist[rows[e] >> BSHIFT], 1);
    }
    __syncthreads();
    for (int b = threadIdx.x; b < nb; b += 256)
        ghist[blockIdx.x * NBMAX + b] = hist[b];
}

// One WG per bucket: exclusive prefix over chunks written back into ghist;
// bucket total -> btot[b].
__global__ __launch_bounds__(256) void colscan_kernel(
        int* __restrict__ ghist, int* __restrict__ btot, int NC, int nb) {
    __shared__ int sh[256];
    const int b = blockIdx.x;
    int run = 0;
    for (int c0 = 0; c0 < NC; c0 += 256) {
        int c = c0 + threadIdx.x;
        int v = (c < NC) ? ghist[c * NBMAX + b] : 0;
        sh[threadIdx.x] = v;
        __syncthreads();
        for (int off = 1; off < 256; off <<= 1) {
            int t = (threadIdx.x >= off) ? sh[threadIdx.x - off] : 0;
            __syncthreads();
            sh[threadIdx.x] += t;
            __syncthreads();
        }
        if (c < NC) ghist[c * NBMAX + b] = run + sh[threadIdx.x] - v;
        run += sh[255];
        __syncthreads();
    }
    if (threadIdx.x == 0) btot[b] = run;
}

// Single block: exclusive-scan btot -> bbase; bbase[nb]=nnz; rp[n_nodes]=nnz.
__global__ __launch_bounds__(1024) void bucketscan_kernel(
        const int* __restrict__ btot, int* __restrict__ bbase,
        int* __restrict__ rp, int nb, int nnz, int n_nodes) {
    __shared__ int sh[1024];
    int v = (threadIdx.x < nb) ? btot[threadIdx.x] : 0;
    sh[threadIdx.x] = v;
    __syncthreads();
    for (int off = 1; off < 1024; off <<= 1) {
        int t = (threadIdx.x >= off) ? sh[threadIdx.x - off] : 0;
        __syncthreads();
        sh[threadIdx.x] += t;
        __syncthreads();
    }
    if (threadIdx.x < nb) bbase[threadIdx.x] = sh[threadIdx.x] - v;
    if (threadIdx.x == 0) { bbase[nb] = nnz; rp[n_nodes] = nnz; }
}

// Single pass: LDS cursors = bbase + chunk prefix; one LDS atomic per edge,
// ZERO global atomics. Payload {(row_low<<COLBITS)|col, val_bits}.
__global__ __launch_bounds__(256) void binscatter2_kernel(
        const int* __restrict__ rows, const int* __restrict__ cols,
        const float* __restrict__ vals, const int* __restrict__ ghist,
        const int* __restrict__ bbase, int2* __restrict__ bin, int nnz, int nb,
        int csz) {
    __shared__ int cur[NBMAX];
    const int chunk = blockIdx.x;
    const long long c0 = (long long)chunk * csz;
    for (int b = threadIdx.x; b < nb; b += 256)
        cur[b] = bbase[b] + ghist[chunk * NBMAX + b];
    __syncthreads();
    for (int i = threadIdx.x; i < csz; i += 256) {
        long long e = c0 + i;
        if (e >= nnz) break;
        int r = rows[e];
        int b = r >> BSHIFT;
        int k = atomicAdd(&cur[b], 1);
        bin[k] = make_int2(((r & (BROWS - 1)) << COLBITS) | cols[e],
                           __float_as_int(vals[e]));
    }
}

// Phase 2 (one WG of 512 per bucket): count rows in LDS, scan (256 lanes),
// WRITE rp for this bucket, then scatter edges into row order.
__global__ __launch_bounds__(512) void finscatter_kernel(
        const int2* __restrict__ bin, const int* __restrict__ bbase,
        int* __restrict__ rp, int2* __restrict__ sce, int n_nodes) {
    __shared__ int cnt[BROWS];
    __shared__ int sh[BROWS];
    __shared__ int cur[BROWS];
    const int row0 = blockIdx.x << BSHIFT;
    const int tid = threadIdx.x;
    if (tid < BROWS) cnt[tid] = 0;
    __syncthreads();
    const int bb = bbase[blockIdx.x];
    const int be = bbase[blockIdx.x + 1];
    for (int p = bb + tid; p < be; p += 512)
        atomicAdd(&cnt[bin[p].x >> COLBITS], 1);
    __syncthreads();
    int v = 0;
    if (tid < BROWS) { v = cnt[tid]; sh[tid] = v; }
    __syncthreads();
    for (int off = 1; off < BROWS; off <<= 1) {
        int t = (tid < BROWS && tid >= off) ? sh[tid - off] : 0;
        __syncthreads();
        if (tid < BROWS) sh[tid] += t;
        __syncthreads();
    }
    if (tid < BROWS) {
        int excl = sh[tid] - v;
        cur[tid] = excl;
        if (row0 + tid < n_nodes) rp[row0 + tid] = bb + excl;   // coalesced rp
    }
    __syncthreads();
    for (int p = bb + tid; p < be; p += 512) {
        int2 e = bin[p];
        int rl = e.x >> COLBITS;
        int k = atomicAdd(&cur[rl], 1);
        sce[bb + k] = make_int2(e.x & ((1 << COLBITS) - 1), e.y);
    }
}

// 2 edges per wave: lanes 0-31 = edge A, lanes 32-63 = edge B; each lane
// covers 2 dims as half2 (row = 32 x half2 = 128B). One gather serves two
// edges. fp32 accum; cross-half shfl_xor reduce; lanes 0-31 store half2.
__global__ __launch_bounds__(256) void spmm_h2_kernel(
        const int* __restrict__ rp, const int2* __restrict__ sce,
        const __half* __restrict__ xin, __half* __restrict__ xnxt,
        int n_nodes) {
    int wid = (int)(((long long)blockIdx.x * blockDim.x + threadIdx.x) >> 6);
    int lane = threadIdx.x & 63;
    if (wid >= n_nodes) return;
    int beg = __builtin_amdgcn_readfirstlane(rp[wid]);
    int end = __builtin_amdgcn_readfirstlane(rp[wid + 1]);
    const unsigned long long* __restrict__ sq = (const unsigned long long*)sce;
    const unsigned int* __restrict__ x2 = (const unsigned int*)xin; // row: 32 u32
    const int hsel = lane >> 5;      // which edge of the pair
    const int dp = lane & 31;        // half2 slot within the row
    float l0 = 0.f, h0 = 0.f, l1 = 0.f, h1 = 0.f;
    int p = beg;
    for (; p + 8 <= end; p += 8) {   // 4 pairs in flight
        unsigned long long u0 = __builtin_nontemporal_load(sq + p + 0 + hsel);
        unsigned long long u1 = __builtin_nontemporal_load(sq + p + 2 + hsel);
        unsigned long long u2 = __builtin_nontemporal_load(sq + p + 4 + hsel);
        unsigned long long u3 = __builtin_nontemporal_load(sq + p + 6 + hsel);
        unsigned int g0 = x2[((int)(unsigned)u0) * 32 + dp];
        unsigned int g1 = x2[((int)(unsigned)u1) * 32 + dp];
        unsigned int g2 = x2[((int)(unsigned)u2) * 32 + dp];
        unsigned int g3 = x2[((int)(unsigned)u3) * 32 + dp];
        float v0 = __int_as_float((int)(u0 >> 32));
        float v1 = __int_as_float((int)(u1 >> 32));
        float v2 = __int_as_float((int)(u2 >> 32));
        float v3 = __int_as_float((int)(u3 >> 32));
        float2 f;
        f = __half22float2(*(__half2*)&g0); l0 = fmaf(v0, f.x, l0); h0 = fmaf(v0, f.y, h0);
        f = __half22float2(*(__half2*)&g1); l1 = fmaf(v1, f.x, l1); h1 = fmaf(v1, f.y, h1);
        f = __half22float2(*(__half2*)&g2); l0 = fmaf(v2, f.x, l0); h0 = fmaf(v2, f.y, h0);
        f = __half22float2(*(__half2*)&g3); l1 = fmaf(v3, f.x, l1); h1 = fmaf(v3, f.y, h1);
    }
    for (; p + 2 <= end; p += 2) {   // pair tail
        unsigned long long u = __builtin_nontemporal_load(sq + p + hsel);
        unsigned int g = x2[((int)(unsigned)u) * 32 + dp];
        float v = __int_as_float((int)(u >> 32));
        float2 f = __half22float2(*(__half2*)&g);
        l0 = fmaf(v, f.x, l0); h0 = fmaf(v, f.y, h0);
    }
    if (p < end) {                   // single leftover edge: high half adds 0
        unsigned long long u = __builtin_nontemporal_load(sq + p);
        unsigned int g = x2[((int)(unsigned)u) * 32 + dp];
        float v = hsel ? 0.f : __int_as_float((int)(u >> 32));
        float2 f = __half22float2(*(__half2*)&g);
        l0 = fmaf(v, f.x, l0); h0 = fmaf(v, f.y, h0);
    }
    float slo = l0 + l1, shi = h0 + h1;
    slo += __shfl_xor(slo, 32);
    shi += __shfl_xor(shi, 32);
    if (lane < 32) {
        __half2 hh = __floats2half2_rn(slo, shi);
        __builtin_nontemporal_store(*(unsigned int*)&hh,
                                    (unsigned int*)xnxt + wid * 32 + dp);
    }
}

// out = 0.25 * (x0+x1+x2+x3)[row] at gathered rows (fp16 -> fp32 sum).
__global__ __launch_bounds__(256) void gather_h_kernel(
        const __half* __restrict__ p0, const __half* __restrict__ p1,
        const __half* __restrict__ p2, const __half* __restrict__ p3,
        const int* __restrict__ users, const int* __restrict__ pos,
        const int* __restrict__ neg, float* __restrict__ out,
        int batch, float scale) {
    long long gid = (long long)blockIdx.x * blockDim.x + threadIdx.x;
    long long per = (long long)batch * EMB_C;
    if (gid >= 3 * per) return;
    int which = (int)(gid / per);
    long long rem = gid - (long long)which * per;
    int b = (int)(rem >> 6);
    int d = (int)(rem & 63);
    long long row;
    if (which == 0)      row = users[b];
    else if (which == 1) row = (long long)N_USER_C + pos[b];
    else                 row = (long long)N_USER_C + neg[b];
    long long idx = row * EMB_C + d;
    out[gid] = scale * (__half2float(p0[idx]) + __half2float(p1[idx]) +
                        __half2float(p2[idx]) + __half2float(p3[idx]));
}

// ======================= fallback (atomic) kernels ========================

__global__ __launch_bounds__(256) void fill_kernel(
        const float4* __restrict__ ue, const float4* __restrict__ ie,
        float4* __restrict__ x0, float4* __restrict__ a,
        float4* __restrict__ b, long long u4, long long t4) {
    long long i = (long long)blockIdx.x * blockDim.x + threadIdx.x;
    if (i >= t4) return;
    float4 v = (i < u4) ? ue[i] : ie[i - u4];
    x0[i] = v;
    a[i] = v;
    b[i] = make_float4(0.f, 0.f, 0.f, 0.f);
}

__global__ __launch_bounds__(256) void spmm_kernel(
        const float* __restrict__ vals, const int* __restrict__ rows,
        const int* __restrict__ cols, const float* __restrict__ xin,
        float* __restrict__ xout, int nnz) {
    long long gid = (long long)blockIdx.x * blockDim.x + threadIdx.x;
    int e = (int)(gid >> 6);
    int d = (int)(gid & 63);
    if (e >= nnz) return;
    unsafeAtomicAdd(&xout[(long long)rows[e] * EMB_C + d],
                    vals[e] * xin[(long long)cols[e] * EMB_C + d]);
}

__global__ __launch_bounds__(256) void acczero_kernel(
        float4* __restrict__ acc, const float4* __restrict__ src,
        float4* __restrict__ tozero, long long n4) {
    long long i = (long long)blockIdx.x * blockDim.x + threadIdx.x;
    if (i >= n4) return;
    float4 a = acc[i], s = src[i];
    a.x += s.x; a.y += s.y; a.z += s.z; a.w += s.w;
    acc[i] = a;
    if (tozero) tozero[i] = make_float4(0.f, 0.f, 0.f, 0.f);
}

__global__ __launch_bounds__(256) void gather_f_kernel(
        const float* __restrict__ acc,
        const int* __restrict__ users, const int* __restrict__ pos,
        const int* __restrict__ neg, float* __restrict__ out,
        int batch, float scale) {
    long long gid = (long long)blockIdx.x * blockDim.x + threadIdx.x;
    long long per = (long long)batch * EMB_C;
    if (gid >= 3 * per) return;
    int which = (int)(gid / per);
    long long rem = gid - (long long)which * per;
    int b = (int)(rem >> 6);
    int d = (int)(rem & 63);
    long long row;
    if (which == 0)      row = users[b];
    else if (which == 1) row = (long long)N_USER_C + pos[b];
    else                 row = (long long)N_USER_C + neg[b];
    out[gid] = scale * acc[row * EMB_C + d];
}

// ================================ driver ==================================

extern "C" void kernel_launch(void* const* d_in, const int* in_sizes, int n_in,
                              void* d_out, int out_size, void* d_ws, size_t ws_size,
                              hipStream_t stream) {
    const float* ue    = (const float*)d_in[0];
    const float* ie    = (const float*)d_in[1];
    const float* vals  = (const float*)d_in[2];
    const int*   rows  = (const int*)d_in[3];
    const int*   cols  = (const int*)d_in[4];
    const int*   users = (const int*)d_in[5];
    const int*   pos   = (const int*)d_in[6];
    const int*   neg   = (const int*)d_in[7];
    float* out = (float*)d_out;

    const int nnz   = in_sizes[2];
    const int batch = in_sizes[5];
    const long long uelems = (long long)in_sizes[0];
    const long long total  = uelems + (long long)in_sizes[1];  // n_nodes * EMB
    const int n_nodes = (int)(total / EMB_C);
    const long long u4 = uelems / 4, t4 = total / 4;

    const int T = 256;
    const int fill_blocks = (int)((t4 + T - 1) / T);
    const int gath_blocks = (int)((3LL * batch * EMB_C + T - 1) / T);
    const int spmm_blocks = (int)(((long long)n_nodes * EMB_C + T - 1) / T);
    const int nb = (n_nodes + BROWS - 1) / BROWS;

    // fp16 layout (bytes): x0..x3 | rp(RN*4) | btot(1024*4) | bbase(1024*4) |
    // ghist(NC*NBMAX*4) | sce(nnz*8) | bin(nnz*8)
    const long long RN = ((n_nodes + 1 + 15) / 16) * 16;
    const size_t xbytes = (size_t)total * 2;
    const size_t fixed = 4 * xbytes + (size_t)(RN + 2048) * 4 + (size_t)nnz * 16;
    const bool fits_nb = (nb <= NBMAX) && (n_nodes <= (1 << COLBITS));

    // Prefer small chunks (occupancy) if ghist fits; else fall back to 8192.
    int csz = 2048;
    int NC = (nnz + csz - 1) / csz;
    if (!fits_nb || ws_size < fixed + (size_t)NC * NBMAX * 4) {
        csz = 8192;
        NC = (nnz + csz - 1) / csz;
    }
    const size_t needH = fixed + (size_t)NC * NBMAX * 4;

    char* wb = (char*)d_ws;

    if (fits_nb && ws_size >= needH) {
        __half* x0 = (__half*)wb;
        __half* x1 = (__half*)(wb + xbytes);
        __half* x2 = (__half*)(wb + 2 * xbytes);
        __half* x3 = (__half*)(wb + 3 * xbytes);
        int*   rp    = (int*)(wb + 4 * xbytes);
        int*   btot  = rp + RN;
        int*   bbase = btot + 1024;
        int*   ghist = bbase + 1024;
        int2*  sce   = (int2*)(ghist + (size_t)NC * NBMAX);
        int2*  bin   = sce + nnz;

        fill_h_kernel<<<fill_blocks, T, 0, stream>>>(
            (const float4*)ue, (const float4*)ie, (ushort4*)x0, u4, t4);

        chunkhist_kernel<<<NC, T, 0, stream>>>(rows, ghist, nnz, nb, csz);
        colscan_kernel<<<nb, T, 0, stream>>>(ghist, btot, NC, nb);
        bucketscan_kernel<<<1, 1024, 0, stream>>>(btot, bbase, rp, nb, nnz, n_nodes);
        binscatter2_kernel<<<NC, T, 0, stream>>>(rows, cols, vals, ghist, bbase,
                                                 bin, nnz, nb, csz);
        finscatter_kernel<<<nb, 512, 0, stream>>>(bin, bbase, rp, sce, n_nodes);

        spmm_h2_kernel<<<spmm_blocks, T, 0, stream>>>(rp, sce, x0, x1, n_nodes);
        spmm_h2_kernel<<<spmm_blocks, T, 0, stream>>>(rp, sce, x1, x2, n_nodes);
        spmm_h2_kernel<<<spmm_blocks, T, 0, stream>>>(rp, sce, x2, x3, n_nodes);

        gather_h_kernel<<<gath_blocks, T, 0, stream>>>(
            x0, x1, x2, x3, users, pos, neg, out, batch, 0.25f);
    } else {
        // ---- Tier C: 3-buffer fp32 atomic fallback ----
        float* cur = (float*)wb;
        float* nxt = cur + total;
        float* acc = nxt + total;
        fill_kernel<<<fill_blocks, T, 0, stream>>>(
            (const float4*)ue, (const float4*)ie,
            (float4*)cur, (float4*)acc, (float4*)nxt, u4, t4);
        const int espmm_blocks = (int)(((long long)nnz * EMB_C + T - 1) / T);
        for (int l = 0; l < 3; ++l) {
            spmm_kernel<<<espmm_blocks, T, 0, stream>>>(vals, rows, cols, cur, nxt, nnz);
            float4* tz = (l < 2) ? (float4*)cur : nullptr;
            acczero_kernel<<<fill_blocks, T, 0, stream>>>(
                (float4*)acc, (const float4*)nxt, tz, t4);
            float* t = cur; cur = nxt; nxt = t;
        }
        gather_f_kernel<<<gath_blocks, T, 0, stream>>>(
            acc, users, pos, neg, out, batch, 0.0625f);
    }
}